// Round 1
// baseline (185.116 us; speedup 1.0000x reference)
//
#include <hip/hip_runtime.h>
#include <hip/hip_bf16.h>

// NT-Xent loss: B=4096, D=128, TEMP=0.5, N2=8192.
// loss = mean_i [ log sum_{j!=i} exp(2*sim_ij) - 2*sim_{i,i^4096} ]
// sim = zn zn^T, zn = rownorm(concat(zi,zj)) cast to bf16 for MFMA.

#define BB 4096
#define N2 8192
#define DD 128

using bf16 = __hip_bfloat16;
typedef __attribute__((ext_vector_type(8))) short short8;   // MFMA A/B frag (8 bf16)
typedef __attribute__((ext_vector_type(4))) float float4v;  // MFMA C/D frag

// ---------------- Kernel 1: normalize + cast to bf16, init accumulators ----
__global__ __launch_bounds__(256) void ntx_norm_kernel(
    const float* __restrict__ zi, const float* __restrict__ zj,
    bf16* __restrict__ zn, float* __restrict__ rowsum, float* __restrict__ pos) {
  const int wave = threadIdx.x >> 6;
  const int lane = threadIdx.x & 63;
  const int row = blockIdx.x * 4 + wave;   // grid = 2048 blocks, 4 rows/block
  const float* src = (row < BB) ? (zi + (size_t)row * DD)
                                : (zj + (size_t)(row - BB) * DD);
  float2 v = ((const float2*)src)[lane];   // 2 floats per lane (128 = 64*2)
  float s = v.x * v.x + v.y * v.y;
  #pragma unroll
  for (int o = 32; o > 0; o >>= 1) s += __shfl_xor(s, o);
  float nrm = fmaxf(sqrtf(s), 1e-8f);      // torch clamp
  float rn = 1.0f / nrm;
  __hip_bfloat162 h2;
  h2.x = __float2bfloat16(v.x * rn);
  h2.y = __float2bfloat16(v.y * rn);
  ((__hip_bfloat162*)(zn + (size_t)row * DD))[lane] = h2;
  if (lane == 0) { rowsum[row] = 0.0f; pos[row] = 0.0f; }
}

// ---------------- Kernel 2: fused sim + sum-exp ----------------------------
// grid: (8 col-splits, 128 row-tiles), block 256 (4 waves).
// Each wave owns 16 rows; iterates 64 col-tiles of 16 within its col split.
__global__ __launch_bounds__(256) void ntx_sim_kernel(
    const bf16* __restrict__ zn, float* __restrict__ rowsum,
    float* __restrict__ pos) {
  const int wave = threadIdx.x >> 6;
  const int lane = threadIdx.x & 63;
  const int quad = lane >> 4;
  const int l15  = lane & 15;

  const int rowBase = blockIdx.y * 64 + wave * 16;
  const int colBase0 = blockIdx.x * 1024;

  const short* zs = (const short*)zn;

  // A fragments for this wave's 16 rows, full K=128 (4 chunks of 32)
  short8 a[4];
  {
    const int arow = rowBase + l15;
    const short* ap = zs + (size_t)arow * DD + quad * 8;
    #pragma unroll
    for (int c = 0; c < 4; c++)
      a[c] = *(const short8*)(ap + c * 32);
  }

  float rs0 = 0.f, rs1 = 0.f, rs2 = 0.f, rs3 = 0.f;

  for (int ct = 0; ct < 64; ct++) {
    const int colBase = colBase0 + ct * 16;
    const int brow = colBase + l15;
    const short* bp = zs + (size_t)brow * DD + quad * 8;
    short8 b0 = *(const short8*)(bp);
    short8 b1 = *(const short8*)(bp + 32);
    short8 b2 = *(const short8*)(bp + 64);
    short8 b3 = *(const short8*)(bp + 96);

    float4v acc = {0.f, 0.f, 0.f, 0.f};
    acc = __builtin_amdgcn_mfma_f32_16x16x32_bf16(a[0], b0, acc, 0, 0, 0);
    acc = __builtin_amdgcn_mfma_f32_16x16x32_bf16(a[1], b1, acc, 0, 0, 0);
    acc = __builtin_amdgcn_mfma_f32_16x16x32_bf16(a[2], b2, acc, 0, 0, 0);
    acc = __builtin_amdgcn_mfma_f32_16x16x32_bf16(a[3], b3, acc, 0, 0, 0);

    // C/D layout: col = lane&15, row = quad*4 + reg  [verified m89/m91]
    const int gc = colBase + l15;
    const int gr0 = rowBase + quad * 4;
    #pragma unroll
    for (int r = 0; r < 4; r++) {
      const int gr = gr0 + r;
      const float v = acc[r];
      float e = __expf(v * 2.0f);          // logits = sim / TEMP = 2*sim
      if (gc == gr) e = 0.0f;              // mask self-diagonal
      if (gc == (gr ^ BB)) pos[gr] = v;    // positive-pair similarity
      if (r == 0) rs0 += e;
      else if (r == 1) rs1 += e;
      else if (r == 2) rs2 += e;
      else rs3 += e;
    }
  }

  // reduce across the 16 lanes holding the same row (xor within lane&15)
  float rs[4] = {rs0, rs1, rs2, rs3};
  #pragma unroll
  for (int r = 0; r < 4; r++) {
    float s = rs[r];
    s += __shfl_xor(s, 1);
    s += __shfl_xor(s, 2);
    s += __shfl_xor(s, 4);
    s += __shfl_xor(s, 8);
    if (l15 == 0) atomicAdd(&rowsum[rowBase + quad * 4 + r], s);
  }
}

// ---------------- Kernel 3: finalize --------------------------------------
__global__ __launch_bounds__(256) void ntx_finalize_kernel(
    const float* __restrict__ rowsum, const float* __restrict__ pos,
    float* __restrict__ out) {
  float s = 0.f;
  for (int i = threadIdx.x; i < N2; i += 256)
    s += logf(rowsum[i]) - pos[i] * 2.0f;
  #pragma unroll
  for (int o = 32; o > 0; o >>= 1) s += __shfl_xor(s, o);
  __shared__ float sm[4];
  const int wave = threadIdx.x >> 6;
  const int lane = threadIdx.x & 63;
  if (lane == 0) sm[wave] = s;
  __syncthreads();
  if (threadIdx.x == 0)
    out[0] = (sm[0] + sm[1] + sm[2] + sm[3]) / (float)N2;
}

extern "C" void kernel_launch(void* const* d_in, const int* in_sizes, int n_in,
                              void* d_out, int out_size, void* d_ws, size_t ws_size,
                              hipStream_t stream) {
  const float* zi = (const float*)d_in[0];
  const float* zj = (const float*)d_in[1];
  float* out = (float*)d_out;

  char* ws = (char*)d_ws;
  bf16* zn = (bf16*)ws;                                   // 8192*128*2 = 2 MB
  float* rowsum = (float*)(ws + (size_t)N2 * DD * 2);     // 32 KB
  float* pos = rowsum + N2;                               // 32 KB

  ntx_norm_kernel<<<N2 / 4, 256, 0, stream>>>(zi, zj, zn, rowsum, pos);
  dim3 grid(8, N2 / 64);
  ntx_sim_kernel<<<grid, 256, 0, stream>>>(zn, rowsum, pos);
  ntx_finalize_kernel<<<1, 256, 0, stream>>>(rowsum, pos, out);
}

// Round 2
// 100.603 us; speedup vs baseline: 1.8401x; 1.8401x over previous
//
#include <hip/hip_runtime.h>
#include <hip/hip_bf16.h>

// NT-Xent loss: B=4096, D=128, TEMP=0.5, N2=8192.
// loss = mean_i [ log sum_{j!=i} exp(2*sim_ij) - 2*pos_i ]
// sim = zn zn^T (bf16 MFMA), pos_i = fp32 cosine(z_i, z_{i^B}).
// Self-diagonal handled by rowsum init = -exp(2*sim_ii_bf16); inner loop
// epilogue is just mul+exp+add per element.

#define BB 4096
#define N2 8192
#define DD 128
#define CSPLIT 16          // column splits
#define CW (N2 / CSPLIT)   // 512 cols per split
#define NCT (CW / 16)      // 32 col-tiles per split

using bf16 = __hip_bfloat16;
typedef __attribute__((ext_vector_type(8))) short short8;   // MFMA A/B frag
typedef __attribute__((ext_vector_type(4))) float float4v;  // MFMA C/D frag

// ---------------- Kernel 1: normalize, cast bf16, pos, rowsum init --------
__global__ __launch_bounds__(256) void ntx_norm_kernel(
    const float* __restrict__ zi, const float* __restrict__ zj,
    bf16* __restrict__ zn, float* __restrict__ rowsum, float* __restrict__ pos) {
  const int wave = threadIdx.x >> 6;
  const int lane = threadIdx.x & 63;
  const int row = blockIdx.x * 4 + wave;   // 2048 blocks, 4 rows/block
  const float* own = (row < BB) ? (zi + (size_t)row * DD)
                                : (zj + (size_t)(row - BB) * DD);
  const float* par = (row < BB) ? (zj + (size_t)row * DD)
                                : (zi + (size_t)(row - BB) * DD);
  float2 v = ((const float2*)own)[lane];
  float2 w = ((const float2*)par)[lane];
  float s1 = v.x * v.x + v.y * v.y;   // |z|^2
  float s2 = w.x * w.x + w.y * w.y;   // |partner|^2
  float s3 = v.x * w.x + v.y * w.y;   // z . partner
  #pragma unroll
  for (int o = 32; o > 0; o >>= 1) {
    s1 += __shfl_xor(s1, o);
    s2 += __shfl_xor(s2, o);
    s3 += __shfl_xor(s3, o);
  }
  float nv = fmaxf(sqrtf(s1), 1e-8f);
  float nw = fmaxf(sqrtf(s2), 1e-8f);
  float rv = 1.0f / nv;
  bf16 bx = __float2bfloat16(v.x * rv);
  bf16 by = __float2bfloat16(v.y * rv);
  __hip_bfloat162 h2; h2.x = bx; h2.y = by;
  ((__hip_bfloat162*)(zn + (size_t)row * DD))[lane] = h2;
  // self-similarity in the SAME precision the MFMA will see (bf16 rounded)
  float fx = __bfloat162float(bx), fy = __bfloat162float(by);
  float sii = fx * fx + fy * fy;
  #pragma unroll
  for (int o = 32; o > 0; o >>= 1) sii += __shfl_xor(sii, o);
  if (lane == 0) {
    rowsum[row] = -__expf(2.0f * sii);   // cancels diagonal term of kernel 2
    pos[row] = s3 / (nv * nw);           // fp32 positive-pair cosine
  }
}

// ---------------- Kernel 2: fused sim + sum-exp ----------------------------
// grid (CSPLIT=16, 32). Block 256 = 4 waves; wave owns 64 rows (4 row-tiles),
// block owns 256 rows. Wave iterates 32 col-tiles of 16 in its split.
// 16 MFMAs per 4 B-loads; B prefetched one tile ahead.
__global__ __launch_bounds__(256) void ntx_sim_kernel(
    const bf16* __restrict__ zn, float* __restrict__ rowsum) {
  const int wave = threadIdx.x >> 6;
  const int lane = threadIdx.x & 63;
  const int quad = lane >> 4;
  const int l15  = lane & 15;
  const short* zs = (const short*)zn;

  const int rowBase = blockIdx.y * 256 + wave * 64;
  const int colBase0 = blockIdx.x * CW;

  // A fragments: 4 row-tiles x 4 K-chunks (64 VGPRs)
  short8 a[4][4];
  #pragma unroll
  for (int t = 0; t < 4; t++) {
    const short* ap = zs + (size_t)(rowBase + t * 16 + l15) * DD + quad * 8;
    #pragma unroll
    for (int c = 0; c < 4; c++) a[t][c] = *(const short8*)(ap + c * 32);
  }

  float rs[4][4];
  #pragma unroll
  for (int t = 0; t < 4; t++)
    #pragma unroll
    for (int r = 0; r < 4; r++) rs[t][r] = 0.0f;

  const short* bbase = zs + (size_t)(colBase0 + l15) * DD + quad * 8;

  short8 b[4];
  #pragma unroll
  for (int c = 0; c < 4; c++) b[c] = *(const short8*)(bbase + c * 32);

  for (int ct = 0; ct < NCT; ct++) {
    // prefetch next B tile (wraps to tile 0 on last iter — harmless)
    const int nct = (ct + 1) & (NCT - 1);
    const short* bp = bbase + (size_t)nct * 16 * DD;
    short8 bn[4];
    #pragma unroll
    for (int c = 0; c < 4; c++) bn[c] = *(const short8*)(bp + c * 32);

    #pragma unroll
    for (int t = 0; t < 4; t++) {
      float4v acc = {0.f, 0.f, 0.f, 0.f};
      acc = __builtin_amdgcn_mfma_f32_16x16x32_bf16(a[t][0], b[0], acc, 0, 0, 0);
      acc = __builtin_amdgcn_mfma_f32_16x16x32_bf16(a[t][1], b[1], acc, 0, 0, 0);
      acc = __builtin_amdgcn_mfma_f32_16x16x32_bf16(a[t][2], b[2], acc, 0, 0, 0);
      acc = __builtin_amdgcn_mfma_f32_16x16x32_bf16(a[t][3], b[3], acc, 0, 0, 0);
      // C/D: col = l15, row = quad*4 + r [m89/m91]; diagonal included,
      // cancelled by rowsum init.
      #pragma unroll
      for (int r = 0; r < 4; r++) rs[t][r] += __expf(acc[r] * 2.0f);
    }

    #pragma unroll
    for (int c = 0; c < 4; c++) b[c] = bn[c];
  }

  // reduce across the 16 lanes sharing each row, then one atomic each
  #pragma unroll
  for (int t = 0; t < 4; t++) {
    #pragma unroll
    for (int r = 0; r < 4; r++) {
      float s = rs[t][r];
      s += __shfl_xor(s, 1);
      s += __shfl_xor(s, 2);
      s += __shfl_xor(s, 4);
      s += __shfl_xor(s, 8);
      if (l15 == 0)
        atomicAdd(&rowsum[rowBase + t * 16 + quad * 4 + r], s);
    }
  }
}

// ---------------- Kernel 3: finalize --------------------------------------
__global__ __launch_bounds__(1024) void ntx_finalize_kernel(
    const float* __restrict__ rowsum, const float* __restrict__ pos,
    float* __restrict__ out) {
  float s = 0.f;
  for (int i = threadIdx.x; i < N2; i += 1024)
    s += __logf(rowsum[i]) - 2.0f * pos[i];
  #pragma unroll
  for (int o = 32; o > 0; o >>= 1) s += __shfl_xor(s, o);
  __shared__ float sm[16];
  const int wave = threadIdx.x >> 6;
  const int lane = threadIdx.x & 63;
  if (lane == 0) sm[wave] = s;
  __syncthreads();
  if (threadIdx.x == 0) {
    float t = 0.f;
    #pragma unroll
    for (int i = 0; i < 16; i++) t += sm[i];
    out[0] = t / (float)N2;
  }
}

extern "C" void kernel_launch(void* const* d_in, const int* in_sizes, int n_in,
                              void* d_out, int out_size, void* d_ws, size_t ws_size,
                              hipStream_t stream) {
  const float* zi = (const float*)d_in[0];
  const float* zj = (const float*)d_in[1];
  float* out = (float*)d_out;

  char* ws = (char*)d_ws;
  bf16* zn = (bf16*)ws;                                   // 8192*128*2 = 2 MB
  float* rowsum = (float*)(ws + (size_t)N2 * DD * 2);     // 32 KB
  float* pos = rowsum + N2;                               // 32 KB

  ntx_norm_kernel<<<N2 / 4, 256, 0, stream>>>(zi, zj, zn, rowsum, pos);
  dim3 grid(CSPLIT, N2 / 256);
  ntx_sim_kernel<<<grid, 256, 0, stream>>>(zn, rowsum);
  ntx_finalize_kernel<<<1, 1024, 0, stream>>>(rowsum, pos, out);
}